// Round 10
// baseline (147.002 us; speedup 1.0000x reference)
//
#include <hip/hip_runtime.h>
#include <hip/hip_bf16.h>
#include <stdint.h>

// Linear4bit R10: chunk-major packed fp4 pre-pass (unchanged) + MX-fp4 GEMM
// with fragment REGISTER double-buffering across the tile barrier: window t
// ds_reads tile t+1's frags (LDS buffer written in window t-1) while MFMAs
// consume frags read in window t-1 -> MFMA burst has no lgkm dependency.
// Triple-buffered LDS, one vmcnt(0)+s_barrier per window. 256x256, 8 waves.

#define M_DIM 8192
#define N_DIM 4096
#define K_MAIN 4096
#define K_TOT 4224
#define NCHUNK 132
#define NT 33

#define XP_OFF   ((size_t)0)
#define WP_OFF   (XP_OFF + (size_t)NCHUNK * M_DIM * 16)
#define SXH_OFF  (WP_OFF + (size_t)NCHUNK * N_DIM * 16)
#define SWH_OFF  (SXH_OFF + (size_t)NT * 2 * M_DIM * 2)
#define WS_NEED  (SWH_OFF + (size_t)NT * 2 * N_DIM * 2)

typedef __attribute__((ext_vector_type(4))) float f32x4;
typedef __attribute__((ext_vector_type(16))) float f32x16;
typedef __attribute__((ext_vector_type(8))) short short8;
typedef __attribute__((ext_vector_type(8))) _Float16 half8;
typedef __attribute__((ext_vector_type(4))) int i32x4;
typedef __attribute__((ext_vector_type(8))) int i32x8;

#define SBAR() asm volatile("s_barrier" ::: "memory")

#define PXP_N (NCHUNK * M_DIM)
#define PWP_N (NCHUNK * N_DIM)
#define TSX_N (NT * 2 * M_DIM / 2)
#define TSW_N (NT * 2 * N_DIM / 2)
#define PACK_TOTAL (PXP_N + PWP_N + TSX_N + TSW_N)

__device__ inline unsigned pack4(i32x4 q) {
    return (q.x & 255) | ((q.y & 255) << 8) | ((q.z & 255) << 16) |
           ((unsigned)(q.w & 255) << 24);
}

__global__ __launch_bounds__(256)
void pack_kernel(const int* __restrict__ xq, const int* __restrict__ sx,
                 const int* __restrict__ w, const int* __restrict__ sfw,
                 const int* __restrict__ lrw, const int* __restrict__ sflr,
                 uint8_t* __restrict__ ws) {
    int t = blockIdx.x * 256 + threadIdx.x;
    if (t < PXP_N) {
        const int g = t >> 13;
        const int m = t & 8191;
        const int gs = (g < 128) ? g : (g - 128);
        const int* src = xq + (size_t)m * 2048 + gs * 16;
        i32x4 o;
        o.x = (int)pack4(*(const i32x4*)(src + 0));
        o.y = (int)pack4(*(const i32x4*)(src + 4));
        o.z = (int)pack4(*(const i32x4*)(src + 8));
        o.w = (int)pack4(*(const i32x4*)(src + 12));
        *(i32x4*)(ws + XP_OFF + ((size_t)g * M_DIM + m) * 16) = o;
    } else if (t < PXP_N + PWP_N) {
        const int i = t - PXP_N;
        const int g = i >> 12;
        const int n = i & 4095;
        const int* src = (g < 128) ? (w + (size_t)n * 2048 + g * 16)
                                   : (lrw + (size_t)n * 64 + (g - 128) * 16);
        i32x4 o;
        o.x = (int)pack4(*(const i32x4*)(src + 0));
        o.y = (int)pack4(*(const i32x4*)(src + 4));
        o.z = (int)pack4(*(const i32x4*)(src + 8));
        o.w = (int)pack4(*(const i32x4*)(src + 12));
        *(i32x4*)(ws + WP_OFF + ((size_t)g * N_DIM + n) * 16) = o;
    } else if (t < PXP_N + PWP_N + TSX_N) {
        int i = t - PXP_N - PWP_N;
        int plane = i >> 12;
        int kt = plane >> 1, h = plane & 1;
        int r2 = (i & 4095) << 1;
        int g0 = kt * 4 + h, g2 = g0 + 2;
        int s0 = (g0 < 128) ? g0 : g0 - 128;
        int s2 = (g2 < 128) ? g2 : g2 - 128;
        unsigned b0 = sx[(size_t)r2 * 128 + s0] & 255;
        unsigned b1 = sx[(size_t)r2 * 128 + s2] & 255;
        unsigned b2 = sx[(size_t)(r2 + 1) * 128 + s0] & 255;
        unsigned b3 = sx[(size_t)(r2 + 1) * 128 + s2] & 255;
        *(unsigned*)(ws + SXH_OFF + (size_t)i * 4) = b0 | (b1 << 8) | (b2 << 16) | (b3 << 24);
    } else if (t < PACK_TOTAL) {
        int i = t - PXP_N - PWP_N - TSX_N;
        int plane = i >> 11;
        int kt = plane >> 1, h = plane & 1;
        int r2 = (i & 2047) << 1;
        int g0 = kt * 4 + h, g2 = g0 + 2;
        unsigned b0, b1, b2, b3;
        if (g0 < 128) { b0 = sfw[(size_t)r2 * 128 + g0] & 255; b2 = sfw[(size_t)(r2 + 1) * 128 + g0] & 255; }
        else          { b0 = sflr[(size_t)r2 * 4 + (g0 - 128)] & 255; b2 = sflr[(size_t)(r2 + 1) * 4 + (g0 - 128)] & 255; }
        if (g2 < 128) { b1 = sfw[(size_t)r2 * 128 + g2] & 255; b3 = sfw[(size_t)(r2 + 1) * 128 + g2] & 255; }
        else          { b1 = sflr[(size_t)r2 * 4 + (g2 - 128)] & 255; b3 = sflr[(size_t)(r2 + 1) * 4 + (g2 - 128)] & 255; }
        *(unsigned*)(ws + SWH_OFF + (size_t)i * 4) = b0 | (b1 << 8) | (b2 << 16) | (b3 << 24);
    }
}

__device__ inline void gload_lds16(const void* g, void* l) {
    __builtin_amdgcn_global_load_lds(
        (const __attribute__((address_space(1))) unsigned int*)g,
        (__attribute__((address_space(3))) unsigned int*)l, 16, 0, 0);
}

// undef-extend i32x4 -> i32x8 (fp4 MFMA reads only the low 4 regs)
__device__ inline i32x8 ext8(i32x4 v) {
    return __builtin_shufflevector(v, v, 0, 1, 2, 3, -1, -1, -1, -1);
}

struct Frags {
    i32x4 a0[4], a1[4], b0[2], b1[2];
};

// One window: prefetch scales(T+1)->san, gload buf o2 (tile T+2), ds_read
// frags(T+1) from buf o1 -> NXT, 16 MFMA on CUR, vmcnt(0), barrier, rotate.
#define WINDOW(T, CUR, NXT)                                                      \
  {                                                                              \
    _Pragma("unroll") for (int mi = 0; mi < 4; ++mi)                             \
        san[mi] = *(const unsigned short*)(psx + mi * 64);                       \
    _Pragma("unroll") for (int ni = 0; ni < 2; ++ni)                             \
        sbn[ni] = *(const unsigned short*)(psw + ni * 64);                       \
    psx += 2 * M_DIM * 2; psw += 2 * N_DIM * 2;                                  \
    if ((T) + 2 < NT) {                                                          \
      char* db = ((wid < 4) ? (char*)As : (char*)Bs) + o2 + cst * 4096;          \
      _Pragma("unroll") for (int q = 0; q < 4; ++q)                              \
          gload_lds16(ga + q * 1024, db + q * 1024);                             \
      ga += gstride;                                                             \
    }                                                                            \
    {                                                                            \
      const char* pa = (const char*)As + o1 + laneoffA;                          \
      const char* pb = (const char*)Bs + o1 + laneoffB;                          \
      _Pragma("unroll") for (int mi = 0; mi < 4; ++mi) {                         \
        NXT.a0[mi] = *(const i32x4*)(pa + mi * 512);                             \
        NXT.a1[mi] = *(const i32x4*)(pa + 8192 + mi * 512);                      \
      }                                                                          \
      _Pragma("unroll") for (int ni = 0; ni < 2; ++ni) {                         \
        NXT.b0[ni] = *(const i32x4*)(pb + ni * 512);                             \
        NXT.b1[ni] = *(const i32x4*)(pb + 8192 + ni * 512);                      \
      }                                                                          \
    }                                                                            \
    __builtin_amdgcn_s_setprio(1);                                               \
    _Pragma("unroll") for (int mi = 0; mi < 4; ++mi)                             \
      _Pragma("unroll") for (int ni = 0; ni < 2; ++ni)                           \
        acc[mi][ni] = __builtin_amdgcn_mfma_scale_f32_32x32x64_f8f6f4(           \
            ext8(CUR.a0[mi]), ext8(CUR.b0[ni]), acc[mi][ni], 4, 4, 0, sa[mi], 0, sb[ni]); \
    _Pragma("unroll") for (int mi = 0; mi < 4; ++mi)                             \
      _Pragma("unroll") for (int ni = 0; ni < 2; ++ni)                           \
        acc[mi][ni] = __builtin_amdgcn_mfma_scale_f32_32x32x64_f8f6f4(           \
            ext8(CUR.a1[mi]), ext8(CUR.b1[ni]), acc[mi][ni], 4, 4, 1, sa[mi], 1, sb[ni]); \
    __builtin_amdgcn_s_setprio(0);                                               \
    asm volatile("s_waitcnt vmcnt(0)" ::: "memory");                             \
    SBAR();                                                                      \
    int _tmp = o0; o0 = o1; o1 = o2; o2 = _tmp;                                  \
    _Pragma("unroll") for (int i = 0; i < 4; ++i) sa[i] = san[i];                \
    sb[0] = sbn[0]; sb[1] = sbn[1];                                              \
  }

__global__ __launch_bounds__(512, 2)
void l4b_mx9(const uint8_t* __restrict__ xp, const uint8_t* __restrict__ wp,
             const uint8_t* __restrict__ sxH, const uint8_t* __restrict__ swH,
             float* __restrict__ out) {
    // LDS: 3 buffers x (A 16KB + B 16KB) = 96KB. [buf][chunk 0..3][row][16B]
    __shared__ __align__(16) uint8_t As[3][4][256][16];
    __shared__ __align__(16) uint8_t Bs[3][4][256][16];

    const int tid = threadIdx.x;
    const int lane = tid & 63;
    const int wid = tid >> 6;
    const int wr = wid >> 2;   // 0..1
    const int wc = wid & 3;    // 0..3

    // XCD-aware bijective swizzle, bn fast axis (A-panels L2-resident per XCD)
    const int bid = blockIdx.x;
    const int wgid = (bid & 7) * 64 + (bid >> 3);
    const int bn = (wgid & 15) * 256;
    const int bm = (wgid >> 4) * 256;

    const int h = lane >> 5, r = lane & 31;

    // loop-carried pointers
    const int cst = wid & 3;  // chunk this wave stages
    const uint8_t* ga = (wid < 4)
        ? xp + ((size_t)cst * M_DIM + bm + lane) * 16
        : wp + ((size_t)cst * N_DIM + bn + lane) * 16;
    const size_t gstride = (wid < 4) ? (size_t)4 * M_DIM * 16 : (size_t)4 * N_DIM * 16;
    const uint8_t* psx = sxH + (size_t)(h * M_DIM + bm + wr * 128 + r) * 2;
    const uint8_t* psw = swH + (size_t)(h * N_DIM + bn + wc * 64 + r) * 2;
    const int laneoffA = h * 4096 + (wr * 128 + r) * 16;
    const int laneoffB = h * 4096 + (wc * 64 + r) * 16;

    f32x16 acc[4][2] = {};
    int sa[4], sb[2], san[4], sbn[2];
    Frags F0, F1;

    // ---- prologue: stage tiles 0,1; scales t0; drain; read frags t0 ----
    {
        char* db = ((wid < 4) ? (char*)As : (char*)Bs) + cst * 4096;
#pragma unroll
        for (int q = 0; q < 4; ++q) gload_lds16(ga + q * 1024, db + q * 1024);
        ga += gstride;
    }
#pragma unroll
    for (int mi = 0; mi < 4; ++mi) sa[mi] = *(const unsigned short*)(psx + mi * 64);
#pragma unroll
    for (int ni = 0; ni < 2; ++ni) sb[ni] = *(const unsigned short*)(psw + ni * 64);
    psx += 2 * M_DIM * 2;
    psw += 2 * N_DIM * 2;
    {
        char* db = ((wid < 4) ? (char*)As : (char*)Bs) + 16384 + cst * 4096;
#pragma unroll
        for (int q = 0; q < 4; ++q) gload_lds16(ga + q * 1024, db + q * 1024);
        ga += gstride;
    }
    asm volatile("s_waitcnt vmcnt(0)" ::: "memory");
    SBAR();
    {
        const char* pa = (const char*)As + laneoffA;
        const char* pb = (const char*)Bs + laneoffB;
#pragma unroll
        for (int mi = 0; mi < 4; ++mi) {
            F0.a0[mi] = *(const i32x4*)(pa + mi * 512);
            F0.a1[mi] = *(const i32x4*)(pa + 8192 + mi * 512);
        }
#pragma unroll
        for (int ni = 0; ni < 2; ++ni) {
            F0.b0[ni] = *(const i32x4*)(pb + ni * 512);
            F0.b1[ni] = *(const i32x4*)(pb + 8192 + ni * 512);
        }
    }

    int o0 = 0, o1 = 16384, o2 = 32768;

    // ---- 16 window pairs (t=0..31), frag sets alternate statically ----
    for (int t = 0; t < NT - 1; t += 2) {
        WINDOW(t, F0, F1);
        WINDOW(t + 1, F1, F0);
    }

    // ---- final window t=32: compute F0, no prefetch ----
    __builtin_amdgcn_s_setprio(1);
#pragma unroll
    for (int mi = 0; mi < 4; ++mi)
#pragma unroll
        for (int ni = 0; ni < 2; ++ni)
            acc[mi][ni] = __builtin_amdgcn_mfma_scale_f32_32x32x64_f8f6f4(
                ext8(F0.a0[mi]), ext8(F0.b0[ni]), acc[mi][ni], 4, 4, 0, sa[mi], 0, sb[ni]);
#pragma unroll
    for (int mi = 0; mi < 4; ++mi)
#pragma unroll
        for (int ni = 0; ni < 2; ++ni)
            acc[mi][ni] = __builtin_amdgcn_mfma_scale_f32_32x32x64_f8f6f4(
                ext8(F0.a1[mi]), ext8(F0.b1[ni]), acc[mi][ni], 4, 4, 1, sa[mi], 1, sb[ni]);
    __builtin_amdgcn_s_setprio(0);

    // epilogue: 32x32 C/D layout col=lane&31, row=(reg&3)+8*(reg>>2)+4*(lane>>5)
#pragma unroll
    for (int mi = 0; mi < 4; ++mi)
#pragma unroll
        for (int ni = 0; ni < 2; ++ni) {
            const int col = bn + wc * 64 + ni * 32 + (lane & 31);
            const int rb = bm + wr * 128 + mi * 32 + 4 * (lane >> 5);
#pragma unroll
            for (int reg = 0; reg < 16; ++reg) {
                const int row = rb + (reg & 3) + 8 * (reg >> 2);
                out[(size_t)row * N_DIM + col] = acc[mi][ni][reg];
            }
        }
}

// ======================= fallback (fused f16 dequant GEMM) =======================
__device__ inline short8 dequant8_f16(i32x4 q, int sf) {
    unsigned b = (unsigned)q.x | ((unsigned)q.y << 8) |
                 ((unsigned)q.z << 16) | ((unsigned)q.w << 24);
    unsigned me = b & 0x07070707u;
    unsigned mo = (b >> 4) & 0x07070707u;
    const unsigned TLO = 0x3E3C3800u;
    const unsigned THI = 0x46444240u;
    unsigned He = __builtin_amdgcn_perm(THI, TLO, me);
    unsigned Ho = __builtin_amdgcn_perm(THI, TLO, mo);
    He |= (b & 0x08080808u) << 4;
    Ho |= (b & 0x80808080u);
    unsigned d0 = __builtin_amdgcn_perm(He, 0u, 0x05010400u);
    unsigned d1 = __builtin_amdgcn_perm(He, 0u, 0x07000600u);
    unsigned d2 = __builtin_amdgcn_perm(Ho, 0u, 0x05010400u);
    unsigned d3 = __builtin_amdgcn_perm(Ho, 0u, 0x07000600u);
    i32x4 di; di.x = (int)d0; di.y = (int)d1; di.z = (int)d2; di.w = (int)d3;
    half8 hh = __builtin_bit_cast(half8, di);
    unsigned short se = (unsigned short)((sf - 112) << 10);
    int srep = (int)((unsigned)se | ((unsigned)se << 16));
    i32x4 si; si.x = srep; si.y = srep; si.z = srep; si.w = srep;
    hh = hh * __builtin_bit_cast(half8, si);
    return __builtin_bit_cast(short8, hh);
}

__global__ __launch_bounds__(256)
void l4b_fused(const int* __restrict__ x_q, const int* __restrict__ scales_x,
               const int* __restrict__ weight, const int* __restrict__ SF_w,
               const int* __restrict__ lrw, const int* __restrict__ SF_lr,
               float* __restrict__ out) {
    __shared__ short As[128 * 64];
    __shared__ short Bs[128 * 64];
    const int tid = threadIdx.x;
    const int lane = tid & 63;
    const int wid = tid >> 6;
    const int wr = wid >> 1, wc = wid & 1;
    const int bm = blockIdx.y * 128, bn = blockIdx.x * 128;
    const int srow = tid >> 3;
    const int scol = (tid & 7) * 8;
    f32x4 acc[4][4] = {};
    for (int kt = 0; kt < K_TOT / 64; ++kt) {
        const int k0 = kt * 64;
        __syncthreads();
#pragma unroll
        for (int it = 0; it < 4; ++it) {
            const int row = it * 32 + srow;
            const int k = k0 + scol;
            const int ksrc = (k < K_MAIN) ? k : (k - K_MAIN);
            i32x4 q = *(const i32x4*)(x_q + (size_t)(bm + row) * 2048 + (ksrc >> 1));
            int sf = scales_x[(size_t)(bm + row) * 128 + (ksrc >> 5)];
            short8 v = dequant8_f16(q, sf);
            unsigned a = (unsigned)(row * 128 + scol * 2) ^ (unsigned)((row & 7) << 4);
            *(short8*)((char*)As + a) = v;
        }
#pragma unroll
        for (int it = 0; it < 4; ++it) {
            const int row = it * 32 + srow;
            const int k = k0 + scol;
            i32x4 q; int sf;
            if (k < K_MAIN) {
                q = *(const i32x4*)(weight + (size_t)(bn + row) * 2048 + (k >> 1));
                sf = SF_w[(size_t)(bn + row) * 128 + (k >> 5)];
            } else {
                q = *(const i32x4*)(lrw + (size_t)(bn + row) * 64 + ((k - K_MAIN) >> 1));
                sf = SF_lr[(size_t)(bn + row) * 4 + ((k - K_MAIN) >> 5)];
            }
            short8 v = dequant8_f16(q, sf);
            unsigned a = (unsigned)(row * 128 + scol * 2) ^ (unsigned)((row & 7) << 4);
            *(short8*)((char*)Bs + a) = v;
        }
        __syncthreads();
#pragma unroll
        for (int ks = 0; ks < 2; ++ks) {
            const int koff = ks * 32 + (lane >> 4) * 8;
            short8 af[4], bfr[4];
#pragma unroll
            for (int mi = 0; mi < 4; ++mi) {
                const int row = wr * 64 + mi * 16 + (lane & 15);
                unsigned a = (unsigned)(row * 128 + koff * 2) ^ (unsigned)((row & 7) << 4);
                af[mi] = *(const short8*)((const char*)As + a);
            }
#pragma unroll
            for (int ni = 0; ni < 4; ++ni) {
                const int row = wc * 64 + ni * 16 + (lane & 15);
                unsigned a = (unsigned)(row * 128 + koff * 2) ^ (unsigned)((row & 7) << 4);
                bfr[ni] = *(const short8*)((const char*)Bs + a);
            }
#pragma unroll
            for (int mi = 0; mi < 4; ++mi)
#pragma unroll
                for (int ni = 0; ni < 4; ++ni)
                    acc[mi][ni] = __builtin_amdgcn_mfma_f32_16x16x32_f16(
                        __builtin_bit_cast(half8, af[mi]),
                        __builtin_bit_cast(half8, bfr[ni]),
                        acc[mi][ni], 0, 0, 0);
        }
    }
#pragma unroll
    for (int mi = 0; mi < 4; ++mi)
#pragma unroll
        for (int ni = 0; ni < 4; ++ni) {
            const int col = bn + wc * 64 + ni * 16 + (lane & 15);
            const int row0 = bm + wr * 64 + mi * 16 + (lane >> 4) * 4;
#pragma unroll
            for (int r2 = 0; r2 < 4; ++r2)
                out[(size_t)(row0 + r2) * N_DIM + col] = acc[mi][ni][r2];
        }
}

extern "C" void kernel_launch(void* const* d_in, const int* in_sizes, int n_in,
                              void* d_out, int out_size, void* d_ws, size_t ws_size,
                              hipStream_t stream) {
    const int* x_q  = (const int*)d_in[0];
    const int* sx   = (const int*)d_in[1];
    const int* w    = (const int*)d_in[2];
    const int* sfw  = (const int*)d_in[3];
    const int* lrw  = (const int*)d_in[4];
    const int* sflr = (const int*)d_in[5];
    float* out = (float*)d_out;

    if (ws_size >= WS_NEED) {
        uint8_t* ws = (uint8_t*)d_ws;
        pack_kernel<<<(PACK_TOTAL + 255) / 256, 256, 0, stream>>>(x_q, sx, w, sfw, lrw, sflr, ws);
        l4b_mx9<<<(M_DIM / 256) * (N_DIM / 256), 512, 0, stream>>>(
            ws + XP_OFF, ws + WP_OFF, ws + SXH_OFF, ws + SWH_OFF, out);
    } else {
        dim3 grid(N_DIM / 128, M_DIM / 128);
        l4b_fused<<<grid, dim3(256), 0, stream>>>(x_q, sx, w, sfw, lrw, sflr, out);
    }
}

// Round 11
// 123.290 us; speedup vs baseline: 1.1923x; 1.1923x over previous
//
#include <hip/hip_runtime.h>
#include <hip/hip_bf16.h>
#include <stdint.h>

// Linear4bit R11: chunk-major packed fp4 pre-pass (unchanged) + hybrid MX-fp4
// GEMM: A staged in LDS (2x16KB dbuf, 4x cross-wave reuse), B loaded DIRECT
// global->VGPR one tile ahead (2x reuse not worth DS-pipe cycles). Cuts DS
// traffic below the MFMA pipe time. 256x256 tile, 8 waves, wave tile 128x64.

#define M_DIM 8192
#define N_DIM 4096
#define K_MAIN 4096
#define K_TOT 4224
#define NCHUNK 132
#define NT 33

#define XP_OFF   ((size_t)0)
#define WP_OFF   (XP_OFF + (size_t)NCHUNK * M_DIM * 16)
#define SXH_OFF  (WP_OFF + (size_t)NCHUNK * N_DIM * 16)
#define SWH_OFF  (SXH_OFF + (size_t)NT * 2 * M_DIM * 2)
#define WS_NEED  (SWH_OFF + (size_t)NT * 2 * N_DIM * 2)

typedef __attribute__((ext_vector_type(4))) float f32x4;
typedef __attribute__((ext_vector_type(16))) float f32x16;
typedef __attribute__((ext_vector_type(8))) short short8;
typedef __attribute__((ext_vector_type(8))) _Float16 half8;
typedef __attribute__((ext_vector_type(4))) int i32x4;
typedef __attribute__((ext_vector_type(8))) int i32x8;

#define SBAR() asm volatile("s_barrier" ::: "memory")

#define PXP_N (NCHUNK * M_DIM)
#define PWP_N (NCHUNK * N_DIM)
#define TSX_N (NT * 2 * M_DIM / 2)
#define TSW_N (NT * 2 * N_DIM / 2)
#define PACK_TOTAL (PXP_N + PWP_N + TSX_N + TSW_N)

__device__ inline unsigned pack4(i32x4 q) {
    return (q.x & 255) | ((q.y & 255) << 8) | ((q.z & 255) << 16) |
           ((unsigned)(q.w & 255) << 24);
}

__global__ __launch_bounds__(256)
void pack_kernel(const int* __restrict__ xq, const int* __restrict__ sx,
                 const int* __restrict__ w, const int* __restrict__ sfw,
                 const int* __restrict__ lrw, const int* __restrict__ sflr,
                 uint8_t* __restrict__ ws) {
    int t = blockIdx.x * 256 + threadIdx.x;
    if (t < PXP_N) {
        const int g = t >> 13;
        const int m = t & 8191;
        const int gs = (g < 128) ? g : (g - 128);
        const int* src = xq + (size_t)m * 2048 + gs * 16;
        i32x4 o;
        o.x = (int)pack4(*(const i32x4*)(src + 0));
        o.y = (int)pack4(*(const i32x4*)(src + 4));
        o.z = (int)pack4(*(const i32x4*)(src + 8));
        o.w = (int)pack4(*(const i32x4*)(src + 12));
        *(i32x4*)(ws + XP_OFF + ((size_t)g * M_DIM + m) * 16) = o;
    } else if (t < PXP_N + PWP_N) {
        const int i = t - PXP_N;
        const int g = i >> 12;
        const int n = i & 4095;
        const int* src = (g < 128) ? (w + (size_t)n * 2048 + g * 16)
                                   : (lrw + (size_t)n * 64 + (g - 128) * 16);
        i32x4 o;
        o.x = (int)pack4(*(const i32x4*)(src + 0));
        o.y = (int)pack4(*(const i32x4*)(src + 4));
        o.z = (int)pack4(*(const i32x4*)(src + 8));
        o.w = (int)pack4(*(const i32x4*)(src + 12));
        *(i32x4*)(ws + WP_OFF + ((size_t)g * N_DIM + n) * 16) = o;
    } else if (t < PXP_N + PWP_N + TSX_N) {
        int i = t - PXP_N - PWP_N;
        int plane = i >> 12;
        int kt = plane >> 1, h = plane & 1;
        int r2 = (i & 4095) << 1;
        int g0 = kt * 4 + h, g2 = g0 + 2;
        int s0 = (g0 < 128) ? g0 : g0 - 128;
        int s2 = (g2 < 128) ? g2 : g2 - 128;
        unsigned b0 = sx[(size_t)r2 * 128 + s0] & 255;
        unsigned b1 = sx[(size_t)r2 * 128 + s2] & 255;
        unsigned b2 = sx[(size_t)(r2 + 1) * 128 + s0] & 255;
        unsigned b3 = sx[(size_t)(r2 + 1) * 128 + s2] & 255;
        *(unsigned*)(ws + SXH_OFF + (size_t)i * 4) = b0 | (b1 << 8) | (b2 << 16) | (b3 << 24);
    } else if (t < PACK_TOTAL) {
        int i = t - PXP_N - PWP_N - TSX_N;
        int plane = i >> 11;
        int kt = plane >> 1, h = plane & 1;
        int r2 = (i & 2047) << 1;
        int g0 = kt * 4 + h, g2 = g0 + 2;
        unsigned b0, b1, b2, b3;
        if (g0 < 128) { b0 = sfw[(size_t)r2 * 128 + g0] & 255; b2 = sfw[(size_t)(r2 + 1) * 128 + g0] & 255; }
        else          { b0 = sflr[(size_t)r2 * 4 + (g0 - 128)] & 255; b2 = sflr[(size_t)(r2 + 1) * 4 + (g0 - 128)] & 255; }
        if (g2 < 128) { b1 = sfw[(size_t)r2 * 128 + g2] & 255; b3 = sfw[(size_t)(r2 + 1) * 128 + g2] & 255; }
        else          { b1 = sflr[(size_t)r2 * 4 + (g2 - 128)] & 255; b3 = sflr[(size_t)(r2 + 1) * 4 + (g2 - 128)] & 255; }
        *(unsigned*)(ws + SWH_OFF + (size_t)i * 4) = b0 | (b1 << 8) | (b2 << 16) | (b3 << 24);
    }
}

__device__ inline void gload_lds16(const void* g, void* l) {
    __builtin_amdgcn_global_load_lds(
        (const __attribute__((address_space(1))) unsigned int*)g,
        (__attribute__((address_space(3))) unsigned int*)l, 16, 0, 0);
}

// undef-extend i32x4 -> i32x8 (fp4 MFMA reads only the low 4 regs)
__device__ inline i32x8 ext8(i32x4 v) {
    return __builtin_shufflevector(v, v, 0, 1, 2, 3, -1, -1, -1, -1);
}

__global__ __launch_bounds__(512, 2)
void l4b_mx10(const uint8_t* __restrict__ xp, const uint8_t* __restrict__ wp,
              const uint8_t* __restrict__ sxH, const uint8_t* __restrict__ swH,
              float* __restrict__ out) {
    // LDS: A only, double-buffered: [buf][chunk 0..3][row 0..255][16B] = 2x16KB
    __shared__ __align__(16) uint8_t As[2][4][256][16];

    const int tid = threadIdx.x;
    const int lane = tid & 63;
    const int wid = tid >> 6;
    const int wr = wid >> 2;   // 0..1
    const int wc = wid & 3;    // 0..3

    // XCD-aware bijective swizzle, bn fast axis (A-panels L2-resident per XCD)
    const int bid = blockIdx.x;
    const int wgid = (bid & 7) * 64 + (bid >> 3);
    const int bn = (wgid & 15) * 256;
    const int bm = (wgid >> 4) * 256;

    const int h = lane >> 5, r = lane & 31;

    // ---- loop-carried pointers ----
    // A staging: wave wid stages chunk c=wid>>1, row-quarters q0=2*(wid&1), q0+1
    const uint8_t* ga = xp + ((size_t)(wid >> 1) * M_DIM + bm + (wid & 1) * 128 + lane) * 16;
    const int lds_base = (wid >> 1) * 4096 + (wid & 1) * 2048;  // within one 16KB buf
    // B direct loads: row bn + wc*64 + ni*32 + r, chunk 4t + kk*2 + h
    const uint8_t* pbg = wp + ((size_t)h * N_DIM + bn + wc * 64 + r) * 16;
    // scales
    const uint8_t* psx = sxH + (size_t)(h * M_DIM + bm + wr * 128 + r) * 2;
    const uint8_t* psw = swH + (size_t)(h * N_DIM + bn + wc * 64 + r) * 2;
    // A fragment ds_read base (within one buf): chunk (kk*2+h), row wr*128+mi*32+r
    const int laneoffA = h * 4096 + (wr * 128 + r) * 16;

    f32x16 acc[4][2] = {};
    int sa[4], sb[2], san[4], sbn[2];
    i32x4 bc[2][2], bnx[2][2];  // [kk][ni] current / next B fragments

    // ---- prologue: stage A(t0), load B(t0)+scales(t0), drain, barrier ----
    gload_lds16(ga, (char*)As + lds_base);
    gload_lds16(ga + 1024, (char*)As + lds_base + 1024);
    ga += (size_t)4 * M_DIM * 16;
#pragma unroll
    for (int kk = 0; kk < 2; ++kk)
#pragma unroll
        for (int ni = 0; ni < 2; ++ni)
            bc[kk][ni] = *(const i32x4*)(pbg + kk * ((size_t)2 * N_DIM * 16) + ni * 512);
    pbg += (size_t)4 * N_DIM * 16;
#pragma unroll
    for (int mi = 0; mi < 4; ++mi) sa[mi] = *(const unsigned short*)(psx + mi * 64);
#pragma unroll
    for (int ni = 0; ni < 2; ++ni) sb[ni] = *(const unsigned short*)(psw + ni * 64);
    psx += 2 * M_DIM * 2;
    psw += 2 * N_DIM * 2;
    asm volatile("s_waitcnt vmcnt(0)" ::: "memory");
    SBAR();

    int cur = 0;
    for (int t = 0; t < NT; ++t) {
        // ---- prefetch tile t+1: A->LDS[cur^1], B->bnx, scales->san/sbn ----
        if (t + 1 < NT) {
            char* db = (char*)As + (cur ^ 1) * 16384 + lds_base;
            gload_lds16(ga, db);
            gload_lds16(ga + 1024, db + 1024);
            ga += (size_t)4 * M_DIM * 16;
#pragma unroll
            for (int kk = 0; kk < 2; ++kk)
#pragma unroll
                for (int ni = 0; ni < 2; ++ni)
                    bnx[kk][ni] = *(const i32x4*)(pbg + kk * ((size_t)2 * N_DIM * 16) + ni * 512);
            pbg += (size_t)4 * N_DIM * 16;
#pragma unroll
            for (int mi = 0; mi < 4; ++mi) san[mi] = *(const unsigned short*)(psx + mi * 64);
#pragma unroll
            for (int ni = 0; ni < 2; ++ni) sbn[ni] = *(const unsigned short*)(psw + ni * 64);
            psx += 2 * M_DIM * 2;
            psw += 2 * N_DIM * 2;
        }

        // ---- ds_read 8 A-frags from buf[cur] ----
        const char* pa = (const char*)As + cur * 16384 + laneoffA;
        i32x4 af0[4], af1[4];
#pragma unroll
        for (int mi = 0; mi < 4; ++mi) {
            af0[mi] = *(const i32x4*)(pa + mi * 512);
            af1[mi] = *(const i32x4*)(pa + 8192 + mi * 512);
        }

        // ---- 16-MFMA cluster (A from LDS regs, B from prefetched regs) ----
        __builtin_amdgcn_s_setprio(1);
#pragma unroll
        for (int mi = 0; mi < 4; ++mi)
#pragma unroll
            for (int ni = 0; ni < 2; ++ni)
                acc[mi][ni] = __builtin_amdgcn_mfma_scale_f32_32x32x64_f8f6f4(
                    ext8(af0[mi]), ext8(bc[0][ni]), acc[mi][ni], 4, 4, 0, sa[mi], 0, sb[ni]);
#pragma unroll
        for (int mi = 0; mi < 4; ++mi)
#pragma unroll
            for (int ni = 0; ni < 2; ++ni)
                acc[mi][ni] = __builtin_amdgcn_mfma_scale_f32_32x32x64_f8f6f4(
                    ext8(af1[mi]), ext8(bc[1][ni]), acc[mi][ni], 4, 4, 1, sa[mi], 1, sb[ni]);
        __builtin_amdgcn_s_setprio(0);

        // ---- one drain + barrier per tile (covers A-stage and B/scale regs) ----
        asm volatile("s_waitcnt vmcnt(0)" ::: "memory");
        SBAR();

        cur ^= 1;
#pragma unroll
        for (int kk = 0; kk < 2; ++kk)
#pragma unroll
            for (int ni = 0; ni < 2; ++ni) bc[kk][ni] = bnx[kk][ni];
#pragma unroll
        for (int i = 0; i < 4; ++i) sa[i] = san[i];
        sb[0] = sbn[0]; sb[1] = sbn[1];
    }

    // epilogue: 32x32 C/D layout col=lane&31, row=(reg&3)+8*(reg>>2)+4*(lane>>5)
#pragma unroll
    for (int mi = 0; mi < 4; ++mi)
#pragma unroll
        for (int ni = 0; ni < 2; ++ni) {
            const int col = bn + wc * 64 + ni * 32 + (lane & 31);
            const int rb = bm + wr * 128 + mi * 32 + 4 * (lane >> 5);
#pragma unroll
            for (int reg = 0; reg < 16; ++reg) {
                const int row = rb + (reg & 3) + 8 * (reg >> 2);
                out[(size_t)row * N_DIM + col] = acc[mi][ni][reg];
            }
        }
}

// ======================= fallback (fused f16 dequant GEMM) =======================
__device__ inline short8 dequant8_f16(i32x4 q, int sf) {
    unsigned b = (unsigned)q.x | ((unsigned)q.y << 8) |
                 ((unsigned)q.z << 16) | ((unsigned)q.w << 24);
    unsigned me = b & 0x07070707u;
    unsigned mo = (b >> 4) & 0x07070707u;
    const unsigned TLO = 0x3E3C3800u;
    const unsigned THI = 0x46444240u;
    unsigned He = __builtin_amdgcn_perm(THI, TLO, me);
    unsigned Ho = __builtin_amdgcn_perm(THI, TLO, mo);
    He |= (b & 0x08080808u) << 4;
    Ho |= (b & 0x80808080u);
    unsigned d0 = __builtin_amdgcn_perm(He, 0u, 0x05010400u);
    unsigned d1 = __builtin_amdgcn_perm(He, 0u, 0x07000600u);
    unsigned d2 = __builtin_amdgcn_perm(Ho, 0u, 0x05010400u);
    unsigned d3 = __builtin_amdgcn_perm(Ho, 0u, 0x07000600u);
    i32x4 di; di.x = (int)d0; di.y = (int)d1; di.z = (int)d2; di.w = (int)d3;
    half8 hh = __builtin_bit_cast(half8, di);
    unsigned short se = (unsigned short)((sf - 112) << 10);
    int srep = (int)((unsigned)se | ((unsigned)se << 16));
    i32x4 si; si.x = srep; si.y = srep; si.z = srep; si.w = srep;
    hh = hh * __builtin_bit_cast(half8, si);
    return __builtin_bit_cast(short8, hh);
}

__global__ __launch_bounds__(256)
void l4b_fused(const int* __restrict__ x_q, const int* __restrict__ scales_x,
               const int* __restrict__ weight, const int* __restrict__ SF_w,
               const int* __restrict__ lrw, const int* __restrict__ SF_lr,
               float* __restrict__ out) {
    __shared__ short As[128 * 64];
    __shared__ short Bs[128 * 64];
    const int tid = threadIdx.x;
    const int lane = tid & 63;
    const int wid = tid >> 6;
    const int wr = wid >> 1, wc = wid & 1;
    const int bm = blockIdx.y * 128, bn = blockIdx.x * 128;
    const int srow = tid >> 3;
    const int scol = (tid & 7) * 8;
    f32x4 acc[4][4] = {};
    for (int kt = 0; kt < K_TOT / 64; ++kt) {
        const int k0 = kt * 64;
        __syncthreads();
#pragma unroll
        for (int it = 0; it < 4; ++it) {
            const int row = it * 32 + srow;
            const int k = k0 + scol;
            const int ksrc = (k < K_MAIN) ? k : (k - K_MAIN);
            i32x4 q = *(const i32x4*)(x_q + (size_t)(bm + row) * 2048 + (ksrc >> 1));
            int sf = scales_x[(size_t)(bm + row) * 128 + (ksrc >> 5)];
            short8 v = dequant8_f16(q, sf);
            unsigned a = (unsigned)(row * 128 + scol * 2) ^ (unsigned)((row & 7) << 4);
            *(short8*)((char*)As + a) = v;
        }
#pragma unroll
        for (int it = 0; it < 4; ++it) {
            const int row = it * 32 + srow;
            const int k = k0 + scol;
            i32x4 q; int sf;
            if (k < K_MAIN) {
                q = *(const i32x4*)(weight + (size_t)(bn + row) * 2048 + (k >> 1));
                sf = SF_w[(size_t)(bn + row) * 128 + (k >> 5)];
            } else {
                q = *(const i32x4*)(lrw + (size_t)(bn + row) * 64 + ((k - K_MAIN) >> 1));
                sf = SF_lr[(size_t)(bn + row) * 4 + ((k - K_MAIN) >> 5)];
            }
            short8 v = dequant8_f16(q, sf);
            unsigned a = (unsigned)(row * 128 + scol * 2) ^ (unsigned)((row & 7) << 4);
            *(short8*)((char*)Bs + a) = v;
        }
        __syncthreads();
#pragma unroll
        for (int ks = 0; ks < 2; ++ks) {
            const int koff = ks * 32 + (lane >> 4) * 8;
            short8 af[4], bfr[4];
#pragma unroll
            for (int mi = 0; mi < 4; ++mi) {
                const int row = wr * 64 + mi * 16 + (lane & 15);
                unsigned a = (unsigned)(row * 128 + koff * 2) ^ (unsigned)((row & 7) << 4);
                af[mi] = *(const short8*)((const char*)As + a);
            }
#pragma unroll
            for (int ni = 0; ni < 4; ++ni) {
                const int row = wc * 64 + ni * 16 + (lane & 15);
                unsigned a = (unsigned)(row * 128 + koff * 2) ^ (unsigned)((row & 7) << 4);
                bfr[ni] = *(const short8*)((const char*)Bs + a);
            }
#pragma unroll
            for (int mi = 0; mi < 4; ++mi)
#pragma unroll
                for (int ni = 0; ni < 4; ++ni)
                    acc[mi][ni] = __builtin_amdgcn_mfma_f32_16x16x32_f16(
                        __builtin_bit_cast(half8, af[mi]),
                        __builtin_bit_cast(half8, bfr[ni]),
                        acc[mi][ni], 0, 0, 0);
        }
    }
#pragma unroll
    for (int mi = 0; mi < 4; ++mi)
#pragma unroll
        for (int ni = 0; ni < 4; ++ni) {
            const int col = bn + wc * 64 + ni * 16 + (lane & 15);
            const int row0 = bm + wr * 64 + mi * 16 + (lane >> 4) * 4;
#pragma unroll
            for (int r2 = 0; r2 < 4; ++r2)
                out[(size_t)(row0 + r2) * N_DIM + col] = acc[mi][ni][r2];
        }
}

extern "C" void kernel_launch(void* const* d_in, const int* in_sizes, int n_in,
                              void* d_out, int out_size, void* d_ws, size_t ws_size,
                              hipStream_t stream) {
    const int* x_q  = (const int*)d_in[0];
    const int* sx   = (const int*)d_in[1];
    const int* w    = (const int*)d_in[2];
    const int* sfw  = (const int*)d_in[3];
    const int* lrw  = (const int*)d_in[4];
    const int* sflr = (const int*)d_in[5];
    float* out = (float*)d_out;

    if (ws_size >= WS_NEED) {
        uint8_t* ws = (uint8_t*)d_ws;
        pack_kernel<<<(PACK_TOTAL + 255) / 256, 256, 0, stream>>>(x_q, sx, w, sfw, lrw, sflr, ws);
        l4b_mx10<<<(M_DIM / 256) * (N_DIM / 256), 512, 0, stream>>>(
            ws + XP_OFF, ws + WP_OFF, ws + SXH_OFF, ws + SWH_OFF, out);
    } else {
        dim3 grid(N_DIM / 128, M_DIM / 128);
        l4b_fused<<<grid, dim3(256), 0, stream>>>(x_q, sx, w, sfw, lrw, sflr, out);
    }
}